// Round 7
// baseline (650.131 us; speedup 1.0000x reference)
//
#include <hip/hip_runtime.h>
#include <hip/hip_bf16.h>

using bf16 = __hip_bfloat16;
typedef __bf16 bf16x8 __attribute__((ext_vector_type(8)));
typedef __bf16 bf16x4 __attribute__((ext_vector_type(4)));
typedef __bf16 bf16x2 __attribute__((ext_vector_type(2)));
typedef float  f32x4  __attribute__((ext_vector_type(4)));

#define B_ 8
#define S_ 2048
#define H_ 1024
#define M_ (B_ * S_)   // 16384
#define N_ (2 * H_)    // 2048
#define K_ 1024
#define CHUNKS_ 32
#define CLEN_ 64       // 32*64 = 2048 = S_

__device__ __forceinline__ bf16x8 load8f(const float* p) {
  const float4 a = *(const float4*)p;
  const float4 b = *(const float4*)(p + 4);
  bf16x8 r;
  r[0] = (__bf16)a.x; r[1] = (__bf16)a.y; r[2] = (__bf16)a.z; r[3] = (__bf16)a.w;
  r[4] = (__bf16)b.x; r[5] = (__bf16)b.y; r[6] = (__bf16)b.z; r[7] = (__bf16)b.w;
  return r;
}

// f32 -> bf16 bulk convert, 8 elems/thread. n must be multiple of 8.
__global__ __launch_bounds__(256)
void cvt_f32_bf16(const float* __restrict__ src, bf16* __restrict__ dst, long n) {
  const long i = ((long)blockIdx.x * 256 + threadIdx.x) * 8;
  if (i >= n) return;
  *(bf16x8*)(dst + i) = load8f(src + i);
}

// ---------------------------------------------------------------------------
// W pack+convert (unchanged from round 5/6):
//   packed row 32g+u    = gate  channel 16g+u   (orig row 16g+u)
//   packed row 32g+16+u = hidden channel 16g+u  (orig row H_+16g+u)
// => acc j=0/1 hold (gate,hidden) of ch x0, j=2/3 of ch x1 per lane.
// ---------------------------------------------------------------------------
__global__ __launch_bounds__(256)
void cvt_pack_w(const float* __restrict__ src, bf16* __restrict__ dst, int nmat) {
  const long idx = (long)blockIdx.x * 256 + threadIdx.x;
  const long e = idx * 8;
  if (e >= (long)nmat * N_ * K_) return;
  const int m = (int)(e / ((long)N_ * K_));
  const long em = e - (long)m * N_ * K_;
  const int prow = (int)(em >> 10);          // packed row 0..2047 (K_=1024)
  const int col  = (int)(em & (K_ - 1));
  const int g = prow >> 5, ty = (prow >> 4) & 1, u = prow & 15;
  const int orow = ty * H_ + g * 16 + u;
  *(bf16x8*)(dst + ((long)m * N_ + prow) * K_ + col) =
      load8f(src + ((long)m * N_ + orow) * K_ + col);
}

// ---------------------------------------------------------------------------
// Scan pointwise math:  h_t = ca*h_{t-1} + cb
// ---------------------------------------------------------------------------
__device__ __forceinline__ float rcpf(float x) { return __builtin_amdgcn_rcpf(x); }

__device__ __forceinline__ void step_coeffs(float gate, float hidden,
                                            float& ca, float& cb) {
  const float e1 = __expf(gate);
  ca = rcpf(1.0f + e1);
  const float z = 1.0f - ca;
  float g;
  if (hidden >= 0.0f) {
    g = hidden + 0.5f;
  } else {
    const float e2 = __expf(hidden);
    g = e2 * rcpf(1.0f + e2);
  }
  cb = z * g;
}

__device__ __forceinline__ float g_of(float x) {
  if (x >= 0.0f) return x + 0.5f;
  const float e = __expf(x);
  return e * rcpf(1.0f + e);
}

// ---------------------------------------------------------------------------
// 256x256 8-phase GEMM + fused minGRU coefficient epilogue, TILE-PAIRED.
//
// Round-7 changes vs round-6:
//   (1) grid 256, each block does 2 tiles (same XCD: sw = xcd*64 + tile*32
//       + idx). After tile-0's K-loop tail: one s_barrier (all waves' LDS
//       reads retired -- each wave's lgkmcnt(0) precedes its last MFMA,
//       which precedes this barrier), then tile-1's 6 prologue STAGEs are
//       issued, then tile-0's VALU epilogue runs WHILE those loads fly,
//       then vmcnt(0)+barrier (drains prologue loads + epilogue stores).
//       Ledger at tile-1's first PH_END_VM(4) is then identical to the
//       original prologue guarantee (tile fully in LDS, next 2 halves may
//       be in flight -> here: fully drained, strictly safer).
//   (2) gh layout interleaved: col 2x = ca, col 2x+1 = cb for channel x.
//       Epilogue does 2x bf16x2 stores per (i,r) (64B contiguous per
//       16-lane group); scan_apply reads one bf16x4 per 2 channels.
//
// K-loop / T1 / T2 / T4 / T5 / phase ledger: unchanged (see round-2).
// ---------------------------------------------------------------------------
#define BK_    64
#define NT_    (K_ / BK_)   // 16
#define LBUF_  65536
#define LBOFF_ 32768
#define LHALF_ 16384

__global__ __launch_bounds__(512, 2)
void gemm256(const bf16* __restrict__ A, const bf16* __restrict__ W,
             const float* __restrict__ bias, bf16* __restrict__ C,
             float2* __restrict__ sAB) {
  __shared__ __align__(16) char lds[131072];
  const int tid  = threadIdx.x;
  const int lane = tid & 63;
  const int wv   = tid >> 6;   // 0..7
  const int wm   = wv >> 2;    // 0..1  (row half)
  const int wn   = wv & 3;     // 0..3  (64-col strip)
  const int r15  = lane & 15;
  const int kq   = lane >> 4;

  // T1: XCD swizzle, 256 blocks, 2 tiles each (both in XCD xcd's chunk).
  const int xcd = blockIdx.x & 7;
  const int idx = blockIdx.x >> 3;   // 0..31

  size_t srcOff[2];
  int dstOff[2];
#pragma unroll
  for (int q = 0; q < 2; ++q) {
    const int t  = q * 512 + tid;                 // 16B chunk id 0..1023
    const int cc = (t & 7) ^ ((t >> 3) & 7);      // pre-swizzled col chunk
    srcOff[q] = (size_t)(t >> 3) * K_ + cc * 8;
    dstOff[q] = q * 8192 + wv * 1024;
  }

#define STAGE(GB, LOFF)                                                        \
  { _Pragma("unroll") for (int q_ = 0; q_ < 2; ++q_)                           \
      __builtin_amdgcn_global_load_lds(                                        \
          (const __attribute__((address_space(1))) void*)((GB) + srcOff[q_]),  \
          (__attribute__((address_space(3))) void*)(lds + (LOFF) + dstOff[q_]),\
          16, 0, 0); }

  const int xsw  = (r15 & 7) << 4;
  const int col0 = (kq * 16) ^ xsw;
  const int col1 = (64 + kq * 16) ^ xsw;
  const int aRow = wm * LHALF_ + r15 * 128;
  const int bRow = LBOFF_ + (wn >> 1) * LHALF_ + ((wn & 1) * 64 + r15) * 128;

  f32x4 acc[8][4];
  bf16x8 aF[4][2], bF[4][2];

#define LD_A(BO)                                                               \
  { _Pragma("unroll") for (int i_ = 0; i_ < 4; ++i_) {                         \
      aF[i_][0] = *(const bf16x8*)(lds + (BO) + i_ * 2048 + col0);             \
      aF[i_][1] = *(const bf16x8*)(lds + (BO) + i_ * 2048 + col1); } }

#define LD_B(J0, BO)                                                           \
  { _Pragma("unroll") for (int j_ = 0; j_ < 2; ++j_) {                         \
      bF[(J0) + j_][0] =                                                       \
          *(const bf16x8*)(lds + (BO) + bRow + ((J0) + j_) * 2048 + col0);     \
      bF[(J0) + j_][1] =                                                       \
          *(const bf16x8*)(lds + (BO) + bRow + ((J0) + j_) * 2048 + col1); } }

#define MFMA_Q(I0, J0)                                                         \
  { _Pragma("unroll") for (int i_ = 0; i_ < 4; ++i_)                           \
    _Pragma("unroll") for (int j_ = 0; j_ < 2; ++j_)                           \
    _Pragma("unroll") for (int k_ = 0; k_ < 2; ++k_)                           \
      acc[(I0) + i_][(J0) + j_] = __builtin_amdgcn_mfma_f32_16x16x32_bf16(     \
          aF[i_][k_], bF[(J0) + j_][k_], acc[(I0) + i_][(J0) + j_], 0, 0, 0); }

#define PH_BAR()                                                               \
  __builtin_amdgcn_sched_barrier(0);                                           \
  __builtin_amdgcn_s_barrier();                                                \
  asm volatile("s_waitcnt lgkmcnt(0)" ::: "memory");                           \
  __builtin_amdgcn_sched_barrier(0);                                           \
  __builtin_amdgcn_s_setprio(1);

#define PH_END()                                                               \
  __builtin_amdgcn_s_setprio(0);                                               \
  __builtin_amdgcn_sched_barrier(0);                                           \
  __builtin_amdgcn_s_barrier();

#define PH_END_VM(N)                                                           \
  __builtin_amdgcn_s_setprio(0);                                               \
  __builtin_amdgcn_sched_barrier(0);                                           \
  asm volatile("s_waitcnt vmcnt(" #N ")" ::: "memory");                        \
  __builtin_amdgcn_s_barrier();

#pragma unroll 1
  for (int tile = 0; tile < 2; ++tile) {
    const int sw = xcd * 64 + tile * 32 + idx;
    const int by = sw >> 3;    // 0..63
    const int bx = sw & 7;     // 0..7
    const int mBase = by * 256;
    const int nBase = bx * 256;
    const bf16* aH[2] = {A + (size_t)mBase * K_, A + (size_t)(mBase + 128) * K_};
    const bf16* wH[2] = {W + (size_t)nBase * K_, W + (size_t)(nBase + 128) * K_};

    if (tile == 0) {
      // Cold prologue: tile0 complete + t1.{B0,A0} in flight.
      STAGE(aH[0], 0);
      STAGE(aH[1], LHALF_);
      STAGE(wH[0], LBOFF_);
      STAGE(wH[1], LBOFF_ + LHALF_);
      STAGE(wH[0] + BK_, LBUF_ + LBOFF_);
      STAGE(aH[0] + BK_, LBUF_);
      asm volatile("s_waitcnt vmcnt(4)" ::: "memory");
      __builtin_amdgcn_s_barrier();
    }
    // (tile 1: prologue was issued during tile-0 epilogue and fully drained.)

#pragma unroll
    for (int i = 0; i < 8; ++i)
#pragma unroll
      for (int j = 0; j < 4; ++j)
#pragma unroll
        for (int r = 0; r < 4; ++r) acc[i][j][r] = 0.0f;

#pragma unroll 1
    for (int t = 0; t < NT_ - 2; t += 2) {
      const int o1 = (t + 1) * BK_, o2 = (t + 2) * BK_, o3 = (t + 3) * BK_;
      // ---- tile t (buf0) ----
      LD_A(aRow); LD_B(0, 0);
      STAGE(aH[1] + o1, LBUF_ + LHALF_);             // t+1.A1
      asm volatile("s_waitcnt lgkmcnt(8)" ::: "memory");
      PH_BAR(); MFMA_Q(0, 0); PH_END();
      LD_B(2, 0);
      STAGE(wH[1] + o1, LBUF_ + LBOFF_ + LHALF_);    // t+1.B1
      PH_BAR(); MFMA_Q(0, 2); PH_END();
      LD_A(aRow + 8192);
      STAGE(wH[0] + o2, LBOFF_);                     // t+2.B0
      PH_BAR(); MFMA_Q(4, 0); PH_END();
      STAGE(aH[0] + o2, 0);                          // t+2.A0
      PH_BAR(); MFMA_Q(4, 2); PH_END_VM(4);          // t+1 landed
      // ---- tile t+1 (buf1) ----
      LD_A(LBUF_ + aRow); LD_B(0, LBUF_);
      STAGE(aH[1] + o2, LHALF_);                     // t+2.A1
      asm volatile("s_waitcnt lgkmcnt(8)" ::: "memory");
      PH_BAR(); MFMA_Q(0, 0); PH_END();
      LD_B(2, LBUF_);
      STAGE(wH[1] + o2, LBOFF_ + LHALF_);            // t+2.B1
      PH_BAR(); MFMA_Q(0, 2); PH_END();
      LD_A(LBUF_ + aRow + 8192);
      STAGE(wH[0] + o3, LBUF_ + LBOFF_);             // t+3.B0
      PH_BAR(); MFMA_Q(4, 0); PH_END();
      STAGE(aH[0] + o3, LBUF_);                      // t+3.A0
      PH_BAR(); MFMA_Q(4, 2); PH_END_VM(4);          // t+2 landed
    }

    // Tail: tiles 14 (buf0) and 15 (buf1).
    {
      const int o1 = (NT_ - 1) * BK_;
      LD_A(aRow); LD_B(0, 0);
      STAGE(aH[1] + o1, LBUF_ + LHALF_);             // t15.A1
      asm volatile("s_waitcnt lgkmcnt(8)" ::: "memory");
      PH_BAR(); MFMA_Q(0, 0); PH_END();
      LD_B(2, 0);
      STAGE(wH[1] + o1, LBUF_ + LBOFF_ + LHALF_);    // t15.B1
      PH_BAR(); MFMA_Q(0, 2); PH_END();
      LD_A(aRow + 8192);
      PH_BAR(); MFMA_Q(4, 0); PH_END();
      PH_BAR(); MFMA_Q(4, 2); PH_END_VM(0);          // t15 fully landed
      LD_A(LBUF_ + aRow); LD_B(0, LBUF_);
      PH_BAR(); MFMA_Q(0, 0); PH_END();
      LD_B(2, LBUF_);
      PH_BAR(); MFMA_Q(0, 2); PH_END();
      LD_A(LBUF_ + aRow + 8192);
      PH_BAR(); MFMA_Q(4, 0); PH_END();
      PH_BAR(); MFMA_Q(4, 2);
      __builtin_amdgcn_s_setprio(0);
    }

    // All waves' LDS reads retired (each wave's lgkmcnt(0) preceded its last
    // MFMA cluster) -> after this barrier LDS may be overwritten.
    __builtin_amdgcn_s_barrier();

    if (tile == 0) {
      // Issue tile-1 prologue NOW; loads fly under the epilogue VALU.
      const int sw1 = xcd * 64 + 32 + idx;
      const int m1 = (sw1 >> 3) * 256, n1 = (sw1 & 7) * 256;
      const bf16* a1[2] = {A + (size_t)m1 * K_, A + (size_t)(m1 + 128) * K_};
      const bf16* w1[2] = {W + (size_t)n1 * K_, W + (size_t)(n1 + 128) * K_};
      STAGE(a1[0], 0);
      STAGE(a1[1], LHALF_);
      STAGE(w1[0], LBOFF_);
      STAGE(w1[1], LBOFF_ + LHALF_);
      STAGE(w1[0] + BK_, LBUF_ + LBOFF_);
      STAGE(a1[0] + BK_, LBUF_);
    }

    // ---------------- fused epilogue (current tile) ----------------
    // C/D layout: col = lane&15 (+16*jj), row = wm*128 + i*16 + kq*4 + r.
    // gh layout: col 2x = ca, col 2x+1 = cb for channel x.
    const int colBase = nBase + wn * 64;      // multiple of 64
    const int x0 = (colBase >> 1) + r15;      // channel for jj pair 0/1
    const int x1 = x0 + 16;                   // channel for jj pair 2/3
    const float bg0 = bias[x0], bh0 = bias[H_ + x0];
    const float bg1 = bias[x1], bh1 = bias[H_ + x1];

    float segA[2][8], segB[2][8];
#pragma unroll
    for (int i = 0; i < 8; ++i) {
      float A0 = 1.f, B0 = 0.f, A1 = 1.f, B1 = 0.f;
      const size_t rw0 = (size_t)(mBase + wm * 128 + i * 16 + kq * 4) * N_;
#pragma unroll
      for (int r = 0; r < 4; ++r) {
        float ca0, cb0, ca1, cb1;
        step_coeffs(acc[i][0][r] + bg0, acc[i][1][r] + bh0, ca0, cb0);
        step_coeffs(acc[i][2][r] + bg1, acc[i][3][r] + bh1, ca1, cb1);
        bf16x2 p0, p1;
        p0[0] = (__bf16)ca0; p0[1] = (__bf16)cb0;
        p1[0] = (__bf16)ca1; p1[1] = (__bf16)cb1;
        const size_t rw = rw0 + (size_t)r * N_;
        *(bf16x2*)(C + rw + colBase + 2 * r15)      = p0;  // ch x0 (ca,cb)
        *(bf16x2*)(C + rw + colBase + 32 + 2 * r15) = p1;  // ch x1 (ca,cb)
        // compose with ROUNDED values (consistent with what apply reads)
        const float fa0 = (float)p0[0], fb0 = (float)p0[1];
        const float fa1 = (float)p1[0], fb1 = (float)p1[1];
        A0 = fa0 * A0; B0 = fa0 * B0 + fb0;
        A1 = fa1 * A1; B1 = fa1 * B1 + fb1;
      }
      segA[0][i] = A0; segB[0][i] = B0;
      segA[1][i] = A1; segB[1][i] = B1;
    }

    // ordered cross-kq compose (rows kq-major within i): result = high∘low.
#pragma unroll
    for (int ch = 0; ch < 2; ++ch)
#pragma unroll
      for (int i = 0; i < 8; ++i) {
        float Av = segA[ch][i], Bv = segB[ch][i];
        {
          const float pA = __shfl_xor(Av, 16, 64);
          const float pB = __shfl_xor(Bv, 16, 64);
          Bv = (lane & 16) ? (Av * pB + Bv) : (pA * Bv + pB);
          Av = Av * pA;
        }
        {
          const float pA = __shfl_xor(Av, 32, 64);
          const float pB = __shfl_xor(Bv, 32, 64);
          Bv = (lane & 32) ? (Av * pB + Bv) : (pA * Bv + pB);
          Av = Av * pA;
        }
        segA[ch][i] = Av; segB[ch][i] = Bv;
      }

    // per-chunk compose over i (chunk c: i in [4c,4c+4)) and write sAB.
    if (kq == 0) {
      const int b_idx = mBase / S_;                       // batch
      const int j0 = ((mBase % S_) + wm * 128) / 64;      // first chunk idx
#pragma unroll
      for (int c = 0; c < 2; ++c) {
#pragma unroll
        for (int ch = 0; ch < 2; ++ch) {
          float Av = 1.f, Bv = 0.f;
#pragma unroll
          for (int i = 4 * c; i < 4 * c + 4; ++i) {
            Av = segA[ch][i] * Av;
            Bv = segA[ch][i] * Bv + segB[ch][i];
          }
          const int x = (ch == 0) ? x0 : x1;
          sAB[(size_t)(j0 + c) * (B_ * H_) + b_idx * 1024 + x] =
              make_float2(Av, Bv);
        }
      }
    }

    if (tile == 0) {
      // Drain tile-1 prologue loads + this epilogue's stores; then tile-1
      // K-loop starts with its full tile + next halves resident in LDS.
      asm volatile("s_waitcnt vmcnt(0)" ::: "memory");
      __builtin_amdgcn_s_barrier();
    }
  }
#undef STAGE
#undef LD_A
#undef LD_B
#undef MFMA_Q
#undef PH_BAR
#undef PH_END
#undef PH_END_VM
}

// ---------------------------------------------------------------------------
// Fused carry + apply. gh layout: col 2x = ca, 2x+1 = cb for channel x ->
// one bf16x4 load covers both of this thread's channels.
//
// ALIASING NOTE: rin may equal rout (in-place residual for l>=1) -> not
// __restrict__; the t-loop is hand-pipelined in groups of 8 (all loads of a
// group before any store) so store->load serialization is avoided while
// staying exact-aliasing-safe.
// ---------------------------------------------------------------------------
__global__ __launch_bounds__(256)
void scan_apply(const bf16* __restrict__ gh, const float2* __restrict__ sAB,
                const float* __restrict__ hprev,
                const float* rin, float* rout, bf16* __restrict__ gout,
                float* __restrict__ finals) {
  const int tx = threadIdx.x, bx = blockIdx.x;
  const int half = bx & 1, b = (bx >> 1) & 7, j = bx >> 4;
  const int h = half * 512 + tx * 2;           // even channel
  const int c = b * 1024 + h;

  float h0, h1;
  {
    const float2 hp = *(const float2*)(hprev + c);
    h0 = g_of(hp.x); h1 = g_of(hp.y);
  }
  for (int jj = 0; jj < j; ++jj) {
    const float4 ab = *(const float4*)(sAB + (size_t)jj * (B_ * H_) + c);
    h0 = ab.x * h0 + ab.y;
    h1 = ab.z * h1 + ab.w;
  }

  const size_t rbase = ((size_t)(b * S_ + j * CLEN_)) * H_ + h;
  const bf16* gbase = gh + ((size_t)(b * S_ + j * CLEN_)) * N_ + 2 * h;
#pragma unroll 1
  for (int tt = 0; tt < CLEN_; tt += 8) {
    bf16x4 cv[8];
    float2 rv[8];
#pragma unroll
    for (int u = 0; u < 8; ++u) {
      const size_t t = (size_t)(tt + u);
      cv[u] = *(const bf16x4*)(gbase + t * N_);        // ca0,cb0,ca1,cb1
      rv[u] = *(const float2*)(rin + rbase + t * H_);
    }
#pragma unroll
    for (int u = 0; u < 8; ++u) {
      const size_t t = (size_t)(tt + u);
      h0 = (float)cv[u][0] * h0 + (float)cv[u][1];
      h1 = (float)cv[u][2] * h1 + (float)cv[u][3];
      const float r0 = h0 + rv[u].x;
      const float r1 = h1 + rv[u].y;
      *(float2*)(rout + rbase + t * H_) = make_float2(r0, r1);
      if (gout) {
        bf16x2 o;
        o[0] = (__bf16)r0; o[1] = (__bf16)r1;
        *(bf16x2*)(gout + rbase + t * H_) = o;
      }
    }
  }
  if (j == CHUNKS_ - 1)
    *(float2*)(finals + c) = make_float2(h0, h1);
}

// ---------------------------------------------------------------------------
extern "C" void kernel_launch(void* const* d_in, const int* in_sizes, int n_in,
                              void* d_out, int out_size, void* d_ws,
                              size_t ws_size, hipStream_t stream) {
  const float* x  = (const float*)d_in[0];
  const float* h0 = (const float*)d_in[1];  // (L,B,1,H)
  const float* W0 = (const float*)d_in[2];  // (2H, D)
  const float* b0 = (const float*)d_in[3];  // (2H,)
  const float* Wl = (const float*)d_in[4];  // (L-1, 2H, H)
  const float* bl = (const float*)d_in[5];  // (L-1, 2H)
  float* out    = (float*)d_out;            // (B,S,H) residual stream, in-place
  float* finals = out + (size_t)M_ * H_;    // (L,B,1,H)

  char* ws = (char*)d_ws;
  bf16* gh   = (bf16*)ws;                   // 64 MB: (M_, 2H) (ca,cb) interleaved
  bf16* bufA = (bf16*)(ws + (64u << 20));   // 32 MB: bf16 A for current layer

  const bool wide = ws_size >= ((size_t)115 << 20);
  // wide:  wb = 4 packed weight mats @96 (16 MB), sAB @112 (2 MB)
  // narrow: per-layer packed weights @96 (4 MB), sAB @101 (2 MB)
  bf16*   wb  = (bf16*)(ws + (96u << 20));
  float2* sAB = (float2*)(ws + ((wide ? 112u : 101u) << 20));

  // x -> bf16 into bufA (layer-0 A). 16M elems.
  cvt_f32_bf16<<<dim3(M_ * K_ / 8 / 256), 256, 0, stream>>>(x, bufA, (long)M_ * K_);
  if (wide) {  // pack+convert all weights once
    cvt_pack_w<<<dim3(N_ * K_ / 8 / 256), 256, 0, stream>>>(W0, wb, 1);
    cvt_pack_w<<<dim3(3 * N_ * K_ / 8 / 256), 256, 0, stream>>>(
        Wl, wb + (size_t)N_ * K_, 3);
  }

  for (int l = 0; l < 4; ++l) {
    const float* Wf = (l == 0) ? W0 : Wl + (size_t)(l - 1) * N_ * K_;
    const float* bi = (l == 0) ? b0 : bl + (size_t)(l - 1) * N_;
    bf16* wl_ptr;
    if (wide) {
      wl_ptr = wb + (size_t)l * N_ * K_;
    } else {
      cvt_pack_w<<<dim3(N_ * K_ / 8 / 256), 256, 0, stream>>>(Wf, wb, 1);
      wl_ptr = wb;
    }
    gemm256<<<dim3(256), 512, 0, stream>>>(bufA, wl_ptr, bi, gh, sAB);
    scan_apply<<<dim3(512), 256, 0, stream>>>(
        gh, sAB, h0 + (size_t)l * B_ * H_, (l == 0) ? x : out, out,
        (l == 3) ? nullptr : bufA, finals + (size_t)l * B_ * H_);
  }
}